// Round 1
// baseline (84.302 us; speedup 1.0000x reference)
//
#include <hip/hip_runtime.h>

// RandomResizedCrop: N=128, C=3, H=W=256, fp32.
// out[n,c,y,x] = bilinear(in[n,c], reflect_clip(affine(y)), reflect_clip(affine(x)))
// ix depends only on (n,x); iy only on (n,y); coords shared across c.

constexpr int N_ = 128, C_ = 3, H_ = 256, W_ = 256;

__device__ __forceinline__ void coord(float scale, float bias, float xf, int size,
                                      int& i0, int& i1, float& w) {
    const float span = (float)size;
    const float two  = 2.0f * span;
    float xs  = (xf + 0.5f) * (2.0f / span) - 1.0f;
    float g   = scale * xs + bias;
    float pre = ((g + 1.0f) * span - 1.0f) * 0.5f;
    float t = fabsf(pre + 0.5f);
    t = t - two * floorf(t * (1.0f / two));   // exact fmod(t, 512) for t >= 0 (pow2 span)
    t = (t > span) ? (two - t) : t;
    t -= 0.5f;
    t = fminf(fmaxf(t, 0.0f), span - 1.0f);
    float f = floorf(t);
    w  = t - f;
    i0 = (int)f;
    i1 = min(i0 + 1, size - 1);
}

__global__ __launch_bounds__(256)
void rrc_kernel(const float* __restrict__ in, const float* __restrict__ wh,
                float* __restrict__ out) {
    const int n       = blockIdx.x >> 3;        // 128 images
    const int ystripe = (blockIdx.x & 7) * 32;  // 8 stripes of 32 rows
    const int t  = threadIdx.x;
    const int xq = t & 63;                      // x-quad index: x = 4*xq..4*xq+3
    const int yl = t >> 6;                      // row-within-group-of-4

    const float w_s = wh[n * 4 + 0];
    const float h_s = wh[n * 4 + 1];
    const float w_b = wh[n * 4 + 2];
    const float h_b = wh[n * 4 + 3];

    // Per-thread x coordinates, computed once, kept in registers.
    int ix0[4], ix1[4];
    float wx[4];
#pragma unroll
    for (int j = 0; j < 4; ++j)
        coord(w_s, w_b, (float)(xq * 4 + j), W_, ix0[j], ix1[j], wx[j]);

    const float* __restrict__ inN  = in  + (size_t)n * C_ * H_ * W_;
    float* __restrict__       outN = out + (size_t)n * C_ * H_ * W_;

    for (int yi = 0; yi < 8; ++yi) {
        const int y = ystripe + yi * 4 + yl;
        int iy0, iy1; float wy;
        coord(h_s, h_b, (float)y, H_, iy0, iy1, wy);
#pragma unroll
        for (int c = 0; c < C_; ++c) {
            const float* __restrict__ row0 = inN + (c * H_ + iy0) * W_;
            const float* __restrict__ row1 = inN + (c * H_ + iy1) * W_;
            float4 o;
            float* op = &o.x;
#pragma unroll
            for (int j = 0; j < 4; ++j) {
                float v00 = row0[ix0[j]];
                float v01 = row0[ix1[j]];
                float v10 = row1[ix0[j]];
                float v11 = row1[ix1[j]];
                float top = v00 + wx[j] * (v01 - v00);
                float bot = v10 + wx[j] * (v11 - v10);
                op[j] = top + wy * (bot - top);
            }
            *reinterpret_cast<float4*>(outN + (c * H_ + y) * W_ + xq * 4) = o;
        }
    }
}

extern "C" void kernel_launch(void* const* d_in, const int* in_sizes, int n_in,
                              void* d_out, int out_size, void* d_ws, size_t ws_size,
                              hipStream_t stream) {
    const float* in = (const float*)d_in[0];
    const float* wh = (const float*)d_in[1];
    float* out      = (float*)d_out;
    (void)in_sizes; (void)n_in; (void)out_size; (void)d_ws; (void)ws_size;

    dim3 grid(N_ * 8);   // 128 images x 8 y-stripes
    dim3 block(256);
    rrc_kernel<<<grid, block, 0, stream>>>(in, wh, out);
}

// Round 2
// 59.960 us; speedup vs baseline: 1.4060x; 1.4060x over previous
//
#include <hip/hip_runtime.h>

// RandomResizedCrop: N=128, C=3, H=W=256, fp32. Latency-bound -> maximize
// wave count (4096 blocks) and loads-in-flight (48 batched gathers/row-group).

constexpr int N_ = 128, C_ = 3, H_ = 256, W_ = 256;
constexpr int HW_ = H_ * W_;

__device__ __forceinline__ void coord(float scale, float bias, float xf, int size,
                                      int& i0, int& i1, float& w) {
    const float span = (float)size;
    const float two  = 2.0f * span;
    float xs  = (xf + 0.5f) * (2.0f / span) - 1.0f;
    float g   = scale * xs + bias;
    float pre = ((g + 1.0f) * span - 1.0f) * 0.5f;
    float t = fabsf(pre + 0.5f);
    t = t - two * floorf(t * (1.0f / two));   // exact fmod(t, 512) for t >= 0 (pow2 span)
    t = (t > span) ? (two - t) : t;
    t -= 0.5f;
    t = fminf(fmaxf(t, 0.0f), span - 1.0f);
    float f = floorf(t);
    w  = t - f;
    i0 = (int)f;
    i1 = min(i0 + 1, size - 1);
}

__global__ __launch_bounds__(256)
void rrc_kernel(const float* __restrict__ in, const float* __restrict__ wh,
                float* __restrict__ out) {
    const int n       = blockIdx.x >> 5;         // 128 images
    const int ystripe = (blockIdx.x & 31) * 8;   // 32 stripes of 8 rows
    const int t  = threadIdx.x;
    const int xq = t & 63;                       // x = 4*xq .. 4*xq+3
    const int yl = t >> 6;                       // 4 row-lanes

    const float w_s = wh[n * 4 + 0];
    const float h_s = wh[n * 4 + 1];
    const float w_b = wh[n * 4 + 2];
    const float h_b = wh[n * 4 + 3];

    // Per-thread x coordinates, computed once.
    int ix0[4], ix1[4];
    float wx[4];
#pragma unroll
    for (int j = 0; j < 4; ++j)
        coord(w_s, w_b, (float)(xq * 4 + j), W_, ix0[j], ix1[j], wx[j]);

    const float* __restrict__ inN  = in  + (size_t)n * C_ * HW_;
    float* __restrict__       outN = out + (size_t)n * C_ * HW_;

#pragma unroll
    for (int yi = 0; yi < 2; ++yi) {
        const int y = ystripe + yi * 4 + yl;
        int iy0, iy1; float wy;
        coord(h_s, h_b, (float)y, H_, iy0, iy1, wy);

        const float* __restrict__ r0 = inN + iy0 * W_;
        const float* __restrict__ r1 = inN + iy1 * W_;

        // Issue all 48 gathers before consuming any -> max loads in flight.
        float v00[C_][4], v01[C_][4], v10[C_][4], v11[C_][4];
#pragma unroll
        for (int c = 0; c < C_; ++c) {
            const int co = c * HW_;
#pragma unroll
            for (int j = 0; j < 4; ++j) {
                v00[c][j] = r0[co + ix0[j]];
                v01[c][j] = r0[co + ix1[j]];
                v10[c][j] = r1[co + ix0[j]];
                v11[c][j] = r1[co + ix1[j]];
            }
        }
#pragma unroll
        for (int c = 0; c < C_; ++c) {
            float4 o;
            float* op = &o.x;
#pragma unroll
            for (int j = 0; j < 4; ++j) {
                float top = v00[c][j] + wx[j] * (v01[c][j] - v00[c][j]);
                float bot = v10[c][j] + wx[j] * (v11[c][j] - v10[c][j]);
                op[j] = top + wy * (bot - top);
            }
            *reinterpret_cast<float4*>(outN + (c * H_ + y) * W_ + xq * 4) = o;
        }
    }
}

extern "C" void kernel_launch(void* const* d_in, const int* in_sizes, int n_in,
                              void* d_out, int out_size, void* d_ws, size_t ws_size,
                              hipStream_t stream) {
    const float* in = (const float*)d_in[0];
    const float* wh = (const float*)d_in[1];
    float* out      = (float*)d_out;
    (void)in_sizes; (void)n_in; (void)out_size; (void)d_ws; (void)ws_size;

    dim3 grid(N_ * 32);  // 128 images x 32 y-stripes of 8 rows
    dim3 block(256);
    rrc_kernel<<<grid, block, 0, stream>>>(in, wh, out);
}

// Round 3
// 35.045 us; speedup vs baseline: 2.4055x; 1.7110x over previous
//
#include <hip/hip_runtime.h>

// RandomResizedCrop N=128,C=3,H=W=256 fp32.
// R2 diagnosis: L1 gather-transaction-bound (96 divergent gathers/thread).
// Fix: stage <=9 input rows x 3ch per 8-row output stripe into LDS with
// coalesced float4 loads; gather from LDS instead (scales<=1 guarantee the
// row span: |iy(y+7)-iy(y)| <= 7*h_s <= 7, +1 for iy1 -> 9 rows max).

constexpr int N_ = 128, C_ = 3, H_ = 256, W_ = 256, HW_ = H_ * W_;
constexpr int ROWS_ = 9;                 // max staged input rows per stripe
constexpr int LDSF_ = C_ * ROWS_ * W_;   // 6912 floats = 27648 B -> 5 blocks/CU

__device__ __forceinline__ void coord(float scale, float bias, float xf, int size,
                                      int& i0, int& i1, float& w) {
    const float span = (float)size;
    const float two  = 2.0f * span;
    float xs  = (xf + 0.5f) * (2.0f / span) - 1.0f;
    float g   = scale * xs + bias;
    float pre = ((g + 1.0f) * span - 1.0f) * 0.5f;
    float t = fabsf(pre + 0.5f);
    t = t - two * floorf(t * (1.0f / two));   // exact fmod(t, 512), pow2 span
    t = (t > span) ? (two - t) : t;
    t -= 0.5f;
    t = fminf(fmaxf(t, 0.0f), span - 1.0f);
    float f = floorf(t);
    w  = t - f;
    i0 = (int)f;
    i1 = min(i0 + 1, size - 1);
}

__global__ __launch_bounds__(256)
void rrc_kernel(const float* __restrict__ in, const float* __restrict__ wh,
                float* __restrict__ out) {
    __shared__ float lds[LDSF_];
    const int n   = blockIdx.x >> 5;         // image
    const int ys  = (blockIdx.x & 31) * 8;   // 8-row output stripe
    const int tid = threadIdx.x;
    const int xq  = tid & 63;                // x-quad: x = 4*xq..4*xq+3
    const int yl  = tid >> 6;                // 4 row-lanes

    const float w_s = wh[n * 4 + 0];
    const float h_s = wh[n * 4 + 1];
    const float w_b = wh[n * 4 + 2];
    const float h_b = wh[n * 4 + 3];

    // All 8 rows' y-coords (unrolled, compile-time r); capture rows yl and
    // yl+4 via predicated select (no runtime array indexing -> stays in regs).
    int rmin = H_ - 1, rmax = 0;
    int my0a = 0, my1a = 0, my0b = 0, my1b = 0;
    float wya = 0.0f, wyb = 0.0f;
#pragma unroll
    for (int r = 0; r < 8; ++r) {
        int a, b; float w;
        coord(h_s, h_b, (float)(ys + r), H_, a, b, w);
        rmin = min(rmin, a);
        rmax = max(rmax, b);
        if (r == yl)     { my0a = a; my1a = b; wya = w; }
        if (r == yl + 4) { my0b = a; my1b = b; wyb = w; }
    }
    const int nrows = rmax - rmin + 1;       // <= 9, block-uniform

    // Stage rows [rmin, rmax] x 3 channels, coalesced float4 (1 KB / wave-instr).
    const float* __restrict__ inN = in + (size_t)n * C_ * HW_;
#pragma unroll
    for (int c = 0; c < C_; ++c) {
        for (int r = yl; r < nrows; r += 4) {
            const float4 v = *reinterpret_cast<const float4*>(
                inN + c * HW_ + (rmin + r) * W_ + xq * 4);
            *reinterpret_cast<float4*>(&lds[(c * ROWS_ + r) * W_ + xq * 4]) = v;
        }
    }
    __syncthreads();

    // Per-thread x coords, once.
    int ix0[4], ix1[4]; float wx[4];
#pragma unroll
    for (int j = 0; j < 4; ++j)
        coord(w_s, w_b, (float)(xq * 4 + j), W_, ix0[j], ix1[j], wx[j]);

    float* __restrict__ outN = out + (size_t)n * C_ * HW_;

#pragma unroll
    for (int g = 0; g < 2; ++g) {
        const int y  = ys + g * 4 + yl;
        const int b0 = ((g ? my0b : my0a) - rmin) * W_;
        const int b1 = ((g ? my1b : my1a) - rmin) * W_;
        const float wyr = g ? wyb : wya;
#pragma unroll
        for (int c = 0; c < C_; ++c) {
            const int co = c * ROWS_ * W_;
            float4 o; float* op = &o.x;
#pragma unroll
            for (int j = 0; j < 4; ++j) {
                const float v00 = lds[co + b0 + ix0[j]];
                const float v01 = lds[co + b0 + ix1[j]];
                const float v10 = lds[co + b1 + ix0[j]];
                const float v11 = lds[co + b1 + ix1[j]];
                const float top = v00 + wx[j] * (v01 - v00);
                const float bot = v10 + wx[j] * (v11 - v10);
                op[j] = top + wyr * (bot - top);
            }
            *reinterpret_cast<float4*>(outN + (c * H_ + y) * W_ + xq * 4) = o;
        }
    }
}

extern "C" void kernel_launch(void* const* d_in, const int* in_sizes, int n_in,
                              void* d_out, int out_size, void* d_ws, size_t ws_size,
                              hipStream_t stream) {
    const float* in = (const float*)d_in[0];
    const float* wh = (const float*)d_in[1];
    float* out      = (float*)d_out;
    (void)in_sizes; (void)n_in; (void)out_size; (void)d_ws; (void)ws_size;

    dim3 grid(N_ * 32);  // 128 images x 32 stripes of 8 rows
    dim3 block(256);
    rrc_kernel<<<grid, block, 0, stream>>>(in, wh, out);
}